// Round 2
// baseline (10430.576 us; speedup 1.0000x reference)
//
#include <hip/hip_runtime.h>
#include <hip/hip_bf16.h>

// Problem constants
constexpr int B_ = 256;
constexpr int N_ = 128;
constexpr int E_ = 256;
constexpr int H_ = 512;
constexpr int T_ = 129;          // N+1
constexpr float NEGV = -1e30f;

__device__ __forceinline__ float sigm(float x) { return 1.0f / (1.0f + __expf(-x)); }

// ---------------------------------------------------------------------------
// node_embeds[b,n,e] = sum_d adj[b,n,d] * Wemb[e,d] + bemb[e]
// rows = B*N = 32768. 16 rows per block, 2048 blocks, 256 threads.
__global__ __launch_bounds__(256)
void k_embed(const float* __restrict__ adj, const float* __restrict__ Wemb,
             const float* __restrict__ bemb, float* __restrict__ ne) {
    __shared__ float Wl[32][E_];   // [kk][e]  32KB
    __shared__ float As[16][33];   // [r][kk]
    const int row0 = blockIdx.x * 16;
    const int tid = threadIdx.x;
    float acc[16];
#pragma unroll
    for (int r = 0; r < 16; ++r) acc[r] = 0.f;

    for (int k0 = 0; k0 < N_; k0 += 32) {
        for (int idx = tid; idx < 32 * E_; idx += 256) {
            int kk = idx >> 8, e = idx & 255;
            Wl[kk][e] = Wemb[e * N_ + k0 + kk];
        }
        for (int idx = tid; idx < 16 * 32; idx += 256) {
            int r = idx >> 5, kk = idx & 31;
            As[r][kk] = adj[(size_t)(row0 + r) * N_ + k0 + kk];
        }
        __syncthreads();
#pragma unroll 8
        for (int kk = 0; kk < 32; ++kk) {
            float w = Wl[kk][tid];
#pragma unroll
            for (int r = 0; r < 16; ++r) acc[r] += As[r][kk] * w;
        }
        __syncthreads();
    }
    float be = bemb[tid];
#pragma unroll
    for (int r = 0; r < 16; ++r)
        ne[(size_t)(row0 + r) * E_ + tid] = acc[r] + be;
}

// ---------------------------------------------------------------------------
// init: zero h0/c/loss, build pos table, fill EOS slot of ext_enc (bf16)
__global__ void k_init(const int* __restrict__ tgt, const float* __restrict__ eos,
                       float* __restrict__ hbuf0, float* __restrict__ cbuf,
                       float* __restrict__ loss, int* __restrict__ pos,
                       __hip_bfloat16* __restrict__ ext) {
    int idx = blockIdx.x * blockDim.x + threadIdx.x;   // grid covers B*H = 131072
    if (idx < B_ * H_) { hbuf0[idx] = 0.f; cbuf[idx] = 0.f; }
    if (idx == 0) loss[0] = 0.f;
    if (idx < B_ * T_) {
        int b = idx / T_, t = idx % T_;
        pos[b * T_ + tgt[b * T_ + t]] = t;
    }
    if (idx < B_ * H_) {
        int b = idx / H_, u = idx % H_;
        ext[((size_t)b * T_ + N_) * H_ + u] = __float2bfloat16(eos[u]);
    }
}

// ---------------------------------------------------------------------------
// decoder teacher-forced inputs: dx[b,t,:] = t==0 ? dstart : (tgt[t-1]==N ? 0 : ne[b,tgt[t-1],:])
__global__ __launch_bounds__(256)
void k_decx(const int* __restrict__ tgt, const float* __restrict__ ne,
            const float* __restrict__ dstart, float* __restrict__ dx) {
    int bt = blockIdx.x;            // b*T + t
    int b = bt / T_, t = bt % T_;
    int e = threadIdx.x;
    float v;
    if (t == 0) v = dstart[e];
    else {
        int tg = tgt[b * T_ + t - 1];
        v = (tg >= N_) ? 0.f : ne[((size_t)b * N_ + tg) * E_ + e];
    }
    dx[(size_t)bt * E_ + e] = v;
}

// ---------------------------------------------------------------------------
// One LSTM step: z = [x_t, h] @ [Wih;Whh]^T + bih + bhh, then cell update.
// Grid: 256 blocks = 8 row-tiles(32) x 32 u-tiles(16). Block 256 threads.
// Tile: 32 rows x 64 cols, cols = 4 gates x 16 u (thread owns all 4 gates of its u).
__global__ __launch_bounds__(256)
void k_step(const float* __restrict__ x_base, int x_stride,
            const float* __restrict__ h_in, float* __restrict__ h_out,
            float* __restrict__ cbuf,
            const float* __restrict__ Wih, const float* __restrict__ Whh,
            const float* __restrict__ bih, const float* __restrict__ bhh,
            __hip_bfloat16* __restrict__ h_save, int save_stride) {
    __shared__ float As[32][33];
    __shared__ float Ws[64][33];
    const int mt = blockIdx.x >> 5, ut = blockIdx.x & 31;
    const int b0 = mt * 32, u0 = ut * 16;
    const int tid = threadIdx.x;
    const int tx = tid & 15, ty = tid >> 4;
    float acc[2][4] = {{0.f,0.f,0.f,0.f},{0.f,0.f,0.f,0.f}};

    const int ar = tid >> 3;              // A row 0..31
    const int ak = (tid & 7) * 4;         // A k-offset
    const int wc = tid >> 2;              // W col 0..63
    const int wk = (tid & 3) * 8;         // W k-offset
    const int wj = ((wc >> 4) << 9) + u0 + (wc & 15);   // global gate row j

    for (int k0 = 0; k0 < E_ + H_; k0 += 32) {
        const bool isx = (k0 < E_);
        if (isx) {
            const float* arow = x_base + (size_t)(b0 + ar) * x_stride + k0;
#pragma unroll
            for (int q = 0; q < 4; ++q) As[ar][ak + q] = arow[ak + q];
            const float* wrow = Wih + (size_t)wj * E_ + k0;
#pragma unroll
            for (int q = 0; q < 8; ++q) Ws[wc][wk + q] = wrow[wk + q];
        } else {
            const float* arow = h_in + (size_t)(b0 + ar) * H_ + (k0 - E_);
#pragma unroll
            for (int q = 0; q < 4; ++q) As[ar][ak + q] = arow[ak + q];
            const float* wrow = Whh + (size_t)wj * H_ + (k0 - E_);
#pragma unroll
            for (int q = 0; q < 8; ++q) Ws[wc][wk + q] = wrow[wk + q];
        }
        __syncthreads();
#pragma unroll
        for (int kk = 0; kk < 32; ++kk) {
            float a0 = As[ty][kk], a1 = As[ty + 16][kk];
#pragma unroll
            for (int g = 0; g < 4; ++g) {
                float w = Ws[g * 16 + tx][kk];
                acc[0][g] += a0 * w;
                acc[1][g] += a1 * w;
            }
        }
        __syncthreads();
    }

    const int u = u0 + tx;
#pragma unroll
    for (int rr = 0; rr < 2; ++rr) {
        int b = b0 + ty + rr * 16;
        float zi = acc[rr][0] + bih[u]           + bhh[u];
        float zf = acc[rr][1] + bih[H_ + u]      + bhh[H_ + u];
        float zg = acc[rr][2] + bih[2 * H_ + u]  + bhh[2 * H_ + u];
        float zo = acc[rr][3] + bih[3 * H_ + u]  + bhh[3 * H_ + u];
        float c_old = cbuf[(size_t)b * H_ + u];
        float cn = sigm(zf) * c_old + sigm(zi) * tanhf(zg);
        float hn = sigm(zo) * tanhf(cn);
        cbuf[(size_t)b * H_ + u] = cn;
        h_out[(size_t)b * H_ + u] = hn;
        h_save[(size_t)b * save_stride + u] = __float2bfloat16(hn);
    }
}

// ---------------------------------------------------------------------------
// Batched attention + masked log-softmax + CE.
// Grid: 256 b x 9 t-tiles (TT=16). Block 512 = 16 groups x 32 lanes.
constexpr int TT = 16;
__global__ __launch_bounds__(512)
void k_attn(const __hip_bfloat16* __restrict__ ext,
            const __hip_bfloat16* __restrict__ hdec,
            const int* __restrict__ pos, const int* __restrict__ tgt,
            float* __restrict__ loss) {
    __shared__ float ht[TT][H_];       // 32KB
    __shared__ float key[H_];          // 2KB
    __shared__ float lg[TT][T_ + 3];   // ~8.4KB
    __shared__ float bl[TT];
    const int b = blockIdx.x / 9;
    const int t0 = (blockIdx.x % 9) * TT;
    const int tid = threadIdx.x;
    const int g = tid >> 5, l = tid & 31;

    for (int idx = tid; idx < TT * H_; idx += 512) {
        int tl = idx >> 9, u = idx & 511;
        int t = t0 + tl;
        ht[tl][u] = (t < T_) ? __bfloat162float(hdec[((size_t)b * T_ + t) * H_ + u]) : 0.f;
    }
    __syncthreads();

    for (int j = 0; j < T_; ++j) {
        key[tid] = __bfloat162float(ext[((size_t)b * T_ + j) * H_ + tid]);
        __syncthreads();
        float s = 0.f;
#pragma unroll
        for (int q = 0; q < H_ / 32; ++q) s += ht[g][l + q * 32] * key[l + q * 32];
        s += __shfl_xor(s, 16); s += __shfl_xor(s, 8); s += __shfl_xor(s, 4);
        s += __shfl_xor(s, 2);  s += __shfl_xor(s, 1);
        if (l == 0) {
            int t = t0 + g;
            lg[g][j] = (t < T_ && pos[b * T_ + j] < t) ? NEGV : s;
        }
        __syncthreads();
    }

    const int t = t0 + g;
    float mx = -3.4e38f;
    for (int j = l; j < T_; j += 32) mx = fmaxf(mx, lg[g][j]);
    mx = fmaxf(mx, __shfl_xor(mx, 16)); mx = fmaxf(mx, __shfl_xor(mx, 8));
    mx = fmaxf(mx, __shfl_xor(mx, 4));  mx = fmaxf(mx, __shfl_xor(mx, 2));
    mx = fmaxf(mx, __shfl_xor(mx, 1));
    float se = 0.f;
    for (int j = l; j < T_; j += 32) se += __expf(lg[g][j] - mx);
    se += __shfl_xor(se, 16); se += __shfl_xor(se, 8); se += __shfl_xor(se, 4);
    se += __shfl_xor(se, 2);  se += __shfl_xor(se, 1);
    float lval = 0.f;
    if (l == 0 && t < T_) {
        int tg = tgt[b * T_ + t];
        lval = mx + __logf(se) - lg[g][tg];
    }
    if (l == 0) bl[g] = (t < T_) ? lval : 0.f;
    __syncthreads();
    if (tid == 0) {
        float s = 0.f;
#pragma unroll
        for (int q = 0; q < TT; ++q) s += bl[q];
        atomicAdd(loss, s);
    }
}

// Output dtype follows the REFERENCE output dtype: jnp.float32 -> float*.
// (Round-1 bug: wrote bf16 into the fp32 slot -> test read a denormal ~0.)
__global__ void k_final(const float* __restrict__ loss, float* __restrict__ out) {
    out[0] = loss[0] / (float)(B_ * T_);
}

// ---------------------------------------------------------------------------
extern "C" void kernel_launch(void* const* d_in, const int* in_sizes, int n_in,
                              void* d_out, int out_size, void* d_ws, size_t ws_size,
                              hipStream_t stream) {
    const float* adj    = (const float*)d_in[0];
    const int*   tgt    = (const int*)d_in[1];
    const float* Wemb   = (const float*)d_in[2];
    const float* bemb   = (const float*)d_in[3];
    const float* eWih   = (const float*)d_in[4];
    const float* eWhh   = (const float*)d_in[5];
    const float* ebih   = (const float*)d_in[6];
    const float* ebhh   = (const float*)d_in[7];
    const float* dWih   = (const float*)d_in[8];
    const float* dWhh   = (const float*)d_in[9];
    const float* dbih   = (const float*)d_in[10];
    const float* dbhh   = (const float*)d_in[11];
    const float* dstart = (const float*)d_in[12];
    const float* eos    = (const float*)d_in[13];

    // workspace layout
    float* ws = (float*)d_ws;
    float* ne   = ws;                                   // B*N*E fp32
    float* dx   = ne + (size_t)B_ * N_ * E_;            // B*T*E fp32
    float* hb0  = dx + (size_t)B_ * T_ * E_;            // B*H
    float* hb1  = hb0 + (size_t)B_ * H_;                // B*H
    float* cb   = hb1 + (size_t)B_ * H_;                // B*H
    float* lacc = cb + (size_t)B_ * H_;                 // 256 floats
    int*   pos  = (int*)(lacc + 256);                   // B*T ints
    __hip_bfloat16* ext  = (__hip_bfloat16*)(pos + B_ * T_ + 256); // B*T*H bf16
    __hip_bfloat16* hdec = ext + (size_t)B_ * T_ * H_;             // B*T*H bf16

    float* hbuf[2] = {hb0, hb1};

    k_embed<<<(B_ * N_) / 16, 256, 0, stream>>>(adj, Wemb, bemb, ne);
    k_init<<<(B_ * H_) / 256, 256, 0, stream>>>(tgt, eos, hb0, cb, lacc, pos, ext);
    k_decx<<<B_ * T_, 256, 0, stream>>>(tgt, ne, dstart, dx);

    // encoder: 128 steps
    for (int t = 0; t < N_; ++t) {
        k_step<<<256, 256, 0, stream>>>(
            ne + (size_t)t * E_, N_ * E_,
            hbuf[t & 1], hbuf[(t + 1) & 1], cb,
            eWih, eWhh, ebih, ebhh,
            ext + (size_t)t * H_, T_ * H_);
    }
    // decoder: 129 steps (h/c carry over; parity continues)
    for (int t = 0; t < T_; ++t) {
        int s = N_ + t;
        k_step<<<256, 256, 0, stream>>>(
            dx + (size_t)t * E_, T_ * E_,
            hbuf[s & 1], hbuf[(s + 1) & 1], cb,
            dWih, dWhh, dbih, dbhh,
            hdec + (size_t)t * H_, T_ * H_);
    }

    k_attn<<<B_ * 9, 512, 0, stream>>>(ext, hdec, pos, tgt, lacc);
    k_final<<<1, 1, 0, stream>>>(lacc, (float*)d_out);
}

// Round 4
// 9717.518 us; speedup vs baseline: 1.0734x; 1.0734x over previous
//
#include <hip/hip_runtime.h>
#include <hip/hip_bf16.h>
#include <hip/hip_cooperative_groups.h>

namespace cg = cooperative_groups;

// Problem constants
constexpr int B_ = 256;
constexpr int N_ = 128;
constexpr int E_ = 256;
constexpr int H_ = 512;
constexpr int T_ = 129;          // N+1
constexpr float NEGV = -1e30f;

typedef __attribute__((ext_vector_type(8))) short bf16x8;
typedef __attribute__((ext_vector_type(4))) float f32x4;

__device__ __forceinline__ float sigm(float x) { return 1.0f / (1.0f + __expf(-x)); }

// f32 -> bf16 bits, round-to-nearest-even
__device__ __forceinline__ short f2bf(float f) {
    union { float f; unsigned int u; } v; v.f = f;
    unsigned int r = (v.u + 0x7FFFu + ((v.u >> 16) & 1u)) >> 16;
    return (short)r;
}
__device__ __forceinline__ float bf2f(ushort s) {
    union { float f; unsigned int u; } v; v.u = ((unsigned int)s) << 16;
    return v.f;
}

// ---------------------------------------------------------------------------
// node_embeds[b,n,e] = sum_d adj[b,n,d] * Wemb[e,d] + bemb[e]  -> bf16
__global__ __launch_bounds__(256)
void k_embed(const float* __restrict__ adj, const float* __restrict__ Wemb,
             const float* __restrict__ bemb, ushort* __restrict__ ne) {
    __shared__ float Wl[32][E_];
    __shared__ float As[16][33];
    const int row0 = blockIdx.x * 16;
    const int tid = threadIdx.x;
    float acc[16];
#pragma unroll
    for (int r = 0; r < 16; ++r) acc[r] = 0.f;

    for (int k0 = 0; k0 < N_; k0 += 32) {
        for (int idx = tid; idx < 32 * E_; idx += 256) {
            int kk = idx >> 8, e = idx & 255;
            Wl[kk][e] = Wemb[e * N_ + k0 + kk];
        }
        for (int idx = tid; idx < 16 * 32; idx += 256) {
            int r = idx >> 5, kk = idx & 31;
            As[r][kk] = adj[(size_t)(row0 + r) * N_ + k0 + kk];
        }
        __syncthreads();
#pragma unroll 8
        for (int kk = 0; kk < 32; ++kk) {
            float w = Wl[kk][tid];
#pragma unroll
            for (int r = 0; r < 16; ++r) acc[r] += As[r][kk] * w;
        }
        __syncthreads();
    }
    float be = bemb[tid];
#pragma unroll
    for (int r = 0; r < 16; ++r)
        ne[(size_t)(row0 + r) * E_ + tid] = (ushort)f2bf(acc[r] + be);
}

// ---------------------------------------------------------------------------
// init: zero h0/loss, build pos table, fill EOS slot of ext (bf16)
__global__ void k_init(const int* __restrict__ tgt, const float* __restrict__ eos,
                       ushort* __restrict__ hbuf0, float* __restrict__ loss,
                       int* __restrict__ pos, ushort* __restrict__ ext) {
    int idx = blockIdx.x * blockDim.x + threadIdx.x;   // grid covers B*H = 131072
    if (idx < B_ * H_) hbuf0[idx] = 0;
    if (idx == 0) loss[0] = 0.f;
    if (idx < B_ * T_) {
        int b = idx / T_, t = idx % T_;
        pos[b * T_ + tgt[b * T_ + t]] = t;
    }
    if (idx < B_ * H_) {
        int b = idx / H_, u = idx % H_;
        ext[((size_t)b * T_ + N_) * H_ + u] = (ushort)f2bf(eos[u]);
    }
}

// ---------------------------------------------------------------------------
// decoder teacher-forced inputs (bf16)
__global__ __launch_bounds__(256)
void k_decx(const int* __restrict__ tgt, const ushort* __restrict__ ne,
            const float* __restrict__ dstart, ushort* __restrict__ dx) {
    int bt = blockIdx.x;            // b*T + t
    int b = bt / T_, t = bt % T_;
    int e = threadIdx.x;
    ushort v;
    if (t == 0) v = (ushort)f2bf(dstart[e]);
    else {
        int tg = tgt[b * T_ + t - 1];
        v = (tg >= N_) ? (ushort)0 : ne[((size_t)b * N_ + tg) * E_ + e];
    }
    dx[(size_t)bt * E_ + e] = v;
}

// ---------------------------------------------------------------------------
// Persistent cooperative recurrence kernel.
// Grid: 256 wgs = 8 batch-tiles(32 rows) x 32 unit-tiles(16 units = 64 gate cols).
// Block: 256 threads = 4 waves; wave g owns gate g (16 cols), both m-frags.
// Weights: 24 bf16 B-frags (96 VGPR) per wave, persistent across a phase.
// c-state: 2 f32 regs/thread, persistent across all 257 steps.
__device__ __forceinline__ void load_w(const float* __restrict__ Wih,
                                       const float* __restrict__ Whh,
                                       const float* __restrict__ bih,
                                       const float* __restrict__ bhh,
                                       int u0, int wave, int l15, int l4, int tid,
                                       bf16x8* w, float* blds) {
    const int grow = wave * H_ + u0 + l15;   // gate row in [4H]
#pragma unroll
    for (int kc = 0; kc < 24; ++kc) {
        const float* src = (kc < 8) ? (Wih + (size_t)grow * E_ + kc * 32 + l4 * 8)
                                    : (Whh + (size_t)grow * H_ + (kc - 8) * 32 + l4 * 8);
        float4 v0 = reinterpret_cast<const float4*>(src)[0];
        float4 v1 = reinterpret_cast<const float4*>(src)[1];
        bf16x8 f;
        f[0] = f2bf(v0.x); f[1] = f2bf(v0.y); f[2] = f2bf(v0.z); f[3] = f2bf(v0.w);
        f[4] = f2bf(v1.x); f[5] = f2bf(v1.y); f[6] = f2bf(v1.z); f[7] = f2bf(v1.w);
        w[kc] = f;
    }
    if (tid < 64) {   // blds[g*16+j]
        int g = tid >> 4, j = tid & 15;
        blds[tid] = bih[g * H_ + u0 + j] + bhh[g * H_ + u0 + j];
    }
}

__global__ __launch_bounds__(256, 1)
void k_recur(const ushort* __restrict__ ne, const ushort* __restrict__ dx,
             const float* __restrict__ eWih, const float* __restrict__ eWhh,
             const float* __restrict__ ebih, const float* __restrict__ ebhh,
             const float* __restrict__ dWih, const float* __restrict__ dWhh,
             const float* __restrict__ dbih, const float* __restrict__ dbhh,
             ushort* __restrict__ hb0, ushort* __restrict__ hb1,
             ushort* __restrict__ ext, ushort* __restrict__ hdec) {
    // LDS: A-tile [kcsub 0..95][row 0..31] 16B slots = 48KB; z exchange; bias
    __shared__ ushort Alds[96 * 32 * 8];
    __shared__ float zlds[4][2][16][17];
    __shared__ float blds[64];

    cg::grid_group grid = cg::this_grid();

    const int wg = blockIdx.x;
    const int bt = wg >> 5, ut = wg & 31;
    const int b0 = bt * 32, u0 = ut * 16;
    const int tid = threadIdx.x;
    const int wave = tid >> 6;          // = gate index (i,f,g,o)
    const int lane = tid & 63;
    const int l15 = lane & 15, l4 = lane >> 4;
    const int cj = tid & 15, cr = tid >> 4;   // cell-update coords: unit j, row r32

    bf16x8 w[24];
    float creg0 = 0.f, creg1 = 0.f;     // c for rows cr and cr+16 (persistent)

    const ushort* hc = hb0;             // h_{t-1}
    ushort*       hn = hb1;             // h_t

    load_w(eWih, eWhh, ebih, ebhh, u0, wave, l15, l4, tid, w, blds);
    __syncthreads();

    for (int t = 0; t < N_ + T_; ++t) {
        const bool enc = (t < N_);
        const int  tt  = enc ? t : (t - N_);

        // ---- stage A-tile: x part (kcs 0..31) then h part (kcs 32..95) ----
        {
            const ushort* xb;
            size_t xstr;
            if (enc) { xb = ne + (size_t)tt * E_; xstr = (size_t)N_ * E_; }
            else     { xb = dx + (size_t)tt * E_; xstr = (size_t)T_ * E_; }
#pragma unroll
            for (int i = 0; i < 12; ++i) {
                int slot = i * 256 + tid;
                int kcs = slot >> 5, row = slot & 31;
                const ushort* src = (i < 4)
                    ? (xb + (size_t)(b0 + row) * xstr + kcs * 8)
                    : (hc + (size_t)(b0 + row) * H_ + (kcs - 32) * 8);
                uint4 v = *reinterpret_cast<const uint4*>(src);
                *reinterpret_cast<uint4*>(&Alds[slot * 8]) = v;
            }
        }
        __syncthreads();

        // ---- MFMA: z[32 x 16cols] for this wave's gate ----
        f32x4 acc0 = {0.f, 0.f, 0.f, 0.f};
        f32x4 acc1 = {0.f, 0.f, 0.f, 0.f};
#pragma unroll
        for (int kc = 0; kc < 24; ++kc) {
            const int sbase = (kc * 4 + l4) * 32;
            bf16x8 a0 = *reinterpret_cast<const bf16x8*>(&Alds[(sbase + l15) * 8]);
            bf16x8 a1 = *reinterpret_cast<const bf16x8*>(&Alds[(sbase + 16 + l15) * 8]);
            acc0 = __builtin_amdgcn_mfma_f32_16x16x32_bf16(a0, w[kc], acc0, 0, 0, 0);
            acc1 = __builtin_amdgcn_mfma_f32_16x16x32_bf16(a1, w[kc], acc1, 0, 0, 0);
        }
        // C/D layout: col = lane&15, row = (lane>>4)*4 + reg  [m89-verified]
#pragma unroll
        for (int q = 0; q < 4; ++q) {
            zlds[wave][0][l4 * 4 + q][l15] = acc0[q];
            zlds[wave][1][l4 * 4 + q][l15] = acc1[q];
        }
        __syncthreads();

        // ---- cell update: thread owns (rows cr, cr+16) x unit cj ----
        ushort* sv = enc ? ext : hdec;
        {
            float zi = zlds[0][0][cr][cj] + blds[cj];
            float zf = zlds[1][0][cr][cj] + blds[16 + cj];
            float zg = zlds[2][0][cr][cj] + blds[32 + cj];
            float zo = zlds[3][0][cr][cj] + blds[48 + cj];
            float cn = sigm(zf) * creg0 + sigm(zi) * tanhf(zg);
            float hv = sigm(zo) * tanhf(cn);
            creg0 = cn;
            ushort hbits = (ushort)f2bf(hv);
            int row = b0 + cr;
            hn[(size_t)row * H_ + u0 + cj] = hbits;
            sv[((size_t)row * T_ + tt) * H_ + u0 + cj] = hbits;
        }
        {
            float zi = zlds[0][1][cr][cj] + blds[cj];
            float zf = zlds[1][1][cr][cj] + blds[16 + cj];
            float zg = zlds[2][1][cr][cj] + blds[32 + cj];
            float zo = zlds[3][1][cr][cj] + blds[48 + cj];
            float cn = sigm(zf) * creg1 + sigm(zi) * tanhf(zg);
            float hv = sigm(zo) * tanhf(cn);
            creg1 = cn;
            ushort hbits = (ushort)f2bf(hv);
            int row = b0 + cr + 16;
            hn[(size_t)row * H_ + u0 + cj] = hbits;
            sv[((size_t)row * T_ + tt) * H_ + u0 + cj] = hbits;
        }

        grid.sync();
        { ushort* tmp = (ushort*)hc; hc = hn; hn = tmp; }

        // phase switch: reload decoder weights (no extra grid sync needed)
        if (t == N_ - 1) {
            load_w(dWih, dWhh, dbih, dbhh, u0, wave, l15, l4, tid, w, blds);
            __syncthreads();
        }
    }
}

// ---------------------------------------------------------------------------
// Batched attention + masked log-softmax + CE (unchanged from passing version)
constexpr int TT = 16;
__global__ __launch_bounds__(512)
void k_attn(const __hip_bfloat16* __restrict__ ext,
            const __hip_bfloat16* __restrict__ hdec,
            const int* __restrict__ pos, const int* __restrict__ tgt,
            float* __restrict__ loss) {
    __shared__ float ht[TT][H_];
    __shared__ float key[H_];
    __shared__ float lg[TT][T_ + 3];
    __shared__ float bl[TT];
    const int b = blockIdx.x / 9;
    const int t0 = (blockIdx.x % 9) * TT;
    const int tid = threadIdx.x;
    const int g = tid >> 5, l = tid & 31;

    for (int idx = tid; idx < TT * H_; idx += 512) {
        int tl = idx >> 9, u = idx & 511;
        int t = t0 + tl;
        ht[tl][u] = (t < T_) ? __bfloat162float(hdec[((size_t)b * T_ + t) * H_ + u]) : 0.f;
    }
    __syncthreads();

    for (int j = 0; j < T_; ++j) {
        key[tid] = __bfloat162float(ext[((size_t)b * T_ + j) * H_ + tid]);
        __syncthreads();
        float s = 0.f;
#pragma unroll
        for (int q = 0; q < H_ / 32; ++q) s += ht[g][l + q * 32] * key[l + q * 32];
        s += __shfl_xor(s, 16); s += __shfl_xor(s, 8); s += __shfl_xor(s, 4);
        s += __shfl_xor(s, 2);  s += __shfl_xor(s, 1);
        if (l == 0) {
            int t = t0 + g;
            lg[g][j] = (t < T_ && pos[b * T_ + j] < t) ? NEGV : s;
        }
        __syncthreads();
    }

    const int t = t0 + g;
    float mx = -3.4e38f;
    for (int j = l; j < T_; j += 32) mx = fmaxf(mx, lg[g][j]);
    mx = fmaxf(mx, __shfl_xor(mx, 16)); mx = fmaxf(mx, __shfl_xor(mx, 8));
    mx = fmaxf(mx, __shfl_xor(mx, 4));  mx = fmaxf(mx, __shfl_xor(mx, 2));
    mx = fmaxf(mx, __shfl_xor(mx, 1));
    float se = 0.f;
    for (int j = l; j < T_; j += 32) se += __expf(lg[g][j] - mx);
    se += __shfl_xor(se, 16); se += __shfl_xor(se, 8); se += __shfl_xor(se, 4);
    se += __shfl_xor(se, 2);  se += __shfl_xor(se, 1);
    float lval = 0.f;
    if (l == 0 && t < T_) {
        int tg = tgt[b * T_ + t];
        lval = mx + __logf(se) - lg[g][tg];
    }
    if (l == 0) bl[g] = (t < T_) ? lval : 0.f;
    __syncthreads();
    if (tid == 0) {
        float s = 0.f;
#pragma unroll
        for (int q = 0; q < TT; ++q) s += bl[q];
        atomicAdd(loss, s);
    }
}

__global__ void k_final(const float* __restrict__ loss, float* __restrict__ out) {
    out[0] = loss[0] / (float)(B_ * T_);
}

// ---------------------------------------------------------------------------
extern "C" void kernel_launch(void* const* d_in, const int* in_sizes, int n_in,
                              void* d_out, int out_size, void* d_ws, size_t ws_size,
                              hipStream_t stream) {
    const float* adj    = (const float*)d_in[0];
    const int*   tgt    = (const int*)d_in[1];
    const float* Wemb   = (const float*)d_in[2];
    const float* bemb   = (const float*)d_in[3];
    const float* eWih   = (const float*)d_in[4];
    const float* eWhh   = (const float*)d_in[5];
    const float* ebih   = (const float*)d_in[6];
    const float* ebhh   = (const float*)d_in[7];
    const float* dWih   = (const float*)d_in[8];
    const float* dWhh   = (const float*)d_in[9];
    const float* dbih   = (const float*)d_in[10];
    const float* dbhh   = (const float*)d_in[11];
    const float* dstart = (const float*)d_in[12];
    const float* eos    = (const float*)d_in[13];

    // workspace layout (bf16 activations)
    char* wsb = (char*)d_ws;
    ushort* ne   = (ushort*)wsb;                         wsb += (size_t)B_ * N_ * E_ * 2;   // 16MB
    ushort* dxp  = (ushort*)wsb;                         wsb += (size_t)B_ * T_ * E_ * 2;   // 16.9MB
    ushort* hb0  = (ushort*)wsb;                         wsb += (size_t)B_ * H_ * 2;
    ushort* hb1  = (ushort*)wsb;                         wsb += (size_t)B_ * H_ * 2;
    ushort* ext  = (ushort*)wsb;                         wsb += (size_t)B_ * T_ * H_ * 2;   // 33.8MB
    ushort* hdec = (ushort*)wsb;                         wsb += (size_t)B_ * T_ * H_ * 2;   // 33.8MB
    int*    pos  = (int*)wsb;                            wsb += (size_t)B_ * T_ * 4;
    float*  lacc = (float*)wsb;

    k_embed<<<(B_ * N_) / 16, 256, 0, stream>>>(adj, Wemb, bemb, ne);
    k_init<<<(B_ * H_) / 256, 256, 0, stream>>>(tgt, eos, hb0, lacc, pos, ext);
    k_decx<<<B_ * T_, 256, 0, stream>>>(tgt, ne, dstart, dxp);

    // persistent cooperative recurrence: 256 wgs (1/CU), 257 grid syncs
    {
        const ushort* a_ne = ne; const ushort* a_dx = dxp;
        void* args[] = {
            (void*)&a_ne, (void*)&a_dx,
            (void*)&eWih, (void*)&eWhh, (void*)&ebih, (void*)&ebhh,
            (void*)&dWih, (void*)&dWhh, (void*)&dbih, (void*)&dbhh,
            (void*)&hb0, (void*)&hb1, (void*)&ext, (void*)&hdec
        };
        hipLaunchCooperativeKernel(reinterpret_cast<const void*>(&k_recur),
                                   dim3(256), dim3(256), args, 0, stream);
    }

    k_attn<<<B_ * 9, 512, 0, stream>>>((const __hip_bfloat16*)ext,
                                       (const __hip_bfloat16*)hdec, pos, tgt, lacc);
    k_final<<<1, 1, 0, stream>>>(lacc, (float*)d_out);
}

// Round 6
// 2343.038 us; speedup vs baseline: 4.4517x; 4.1474x over previous
//
#include <hip/hip_runtime.h>
#include <hip/hip_bf16.h>

// Problem constants
constexpr int B_ = 256;
constexpr int N_ = 128;
constexpr int E_ = 256;
constexpr int H_ = 512;
constexpr int T_ = 129;          // N+1
constexpr float NEGV = -1e30f;

typedef __attribute__((ext_vector_type(8))) short bf16x8;
typedef __attribute__((ext_vector_type(4))) float f32x4;

__device__ __forceinline__ float sigm(float x) { return 1.0f / (1.0f + __expf(-x)); }

// f32 -> bf16 bits, round-to-nearest-even
__device__ __forceinline__ short f2bf(float f) {
    union { float f; unsigned int u; } v; v.f = f;
    unsigned int r = (v.u + 0x7FFFu + ((v.u >> 16) & 1u)) >> 16;
    return (short)r;
}

// ---------------------------------------------------------------------------
// node_embeds[b,n,e] = sum_d adj[b,n,d] * Wemb[e,d] + bemb[e]  -> bf16
__global__ __launch_bounds__(256)
void k_embed(const float* __restrict__ adj, const float* __restrict__ Wemb,
             const float* __restrict__ bemb, ushort* __restrict__ ne) {
    __shared__ float Wl[32][E_];
    __shared__ float As[16][33];
    const int row0 = blockIdx.x * 16;
    const int tid = threadIdx.x;
    float acc[16];
#pragma unroll
    for (int r = 0; r < 16; ++r) acc[r] = 0.f;

    for (int k0 = 0; k0 < N_; k0 += 32) {
        for (int idx = tid; idx < 32 * E_; idx += 256) {
            int kk = idx >> 8, e = idx & 255;
            Wl[kk][e] = Wemb[e * N_ + k0 + kk];
        }
        for (int idx = tid; idx < 16 * 32; idx += 256) {
            int r = idx >> 5, kk = idx & 31;
            As[r][kk] = adj[(size_t)(row0 + r) * N_ + k0 + kk];
        }
        __syncthreads();
#pragma unroll 8
        for (int kk = 0; kk < 32; ++kk) {
            float w = Wl[kk][tid];
#pragma unroll
            for (int r = 0; r < 16; ++r) acc[r] += As[r][kk] * w;
        }
        __syncthreads();
    }
    float be = bemb[tid];
#pragma unroll
    for (int r = 0; r < 16; ++r)
        ne[(size_t)(row0 + r) * E_ + tid] = (ushort)f2bf(acc[r] + be);
}

// ---------------------------------------------------------------------------
// init: zero h0/c/loss, build pos table, fill EOS slot of ext (bf16)
__global__ void k_init(const int* __restrict__ tgt, const float* __restrict__ eos,
                       ushort* __restrict__ hbuf0, float* __restrict__ cbuf,
                       float* __restrict__ loss, int* __restrict__ pos,
                       ushort* __restrict__ ext) {
    int idx = blockIdx.x * blockDim.x + threadIdx.x;   // grid covers B*H = 131072
    if (idx < B_ * H_) { hbuf0[idx] = 0; cbuf[idx] = 0.f; }
    if (idx == 0) loss[0] = 0.f;
    if (idx < B_ * T_) {
        int b = idx / T_, t = idx % T_;
        pos[b * T_ + tgt[b * T_ + t]] = t;
    }
    if (idx < B_ * H_) {
        int b = idx / H_, u = idx % H_;
        ext[((size_t)b * T_ + N_) * H_ + u] = (ushort)f2bf(eos[u]);
    }
}

// ---------------------------------------------------------------------------
// decoder teacher-forced inputs (bf16)
__global__ __launch_bounds__(256)
void k_decx(const int* __restrict__ tgt, const ushort* __restrict__ ne,
            const float* __restrict__ dstart, ushort* __restrict__ dx) {
    int bt = blockIdx.x;            // b*T + t
    int b = bt / T_, t = bt % T_;
    int e = threadIdx.x;
    ushort v;
    if (t == 0) v = (ushort)f2bf(dstart[e]);
    else {
        int tg = tgt[b * T_ + t - 1];
        v = (tg >= N_) ? (ushort)0 : ne[((size_t)b * N_ + tg) * E_ + e];
    }
    dx[(size_t)bt * E_ + e] = v;
}

// ---------------------------------------------------------------------------
// Weight pre-pack: both phases -> bf16 fragments in the exact per-thread order
// k_step consumes: wpack[phase][ut][wave][kc][lane] (16B frags; coalesced loads).
// Fragment contents identical to R2's load_w (which passed correctness).
__global__ __launch_bounds__(256)
void k_wprep(const float* __restrict__ eWih, const float* __restrict__ eWhh,
             const float* __restrict__ dWih, const float* __restrict__ dWhh,
             ushort* __restrict__ wpack) {
    int gid = blockIdx.x * 256 + threadIdx.x;      // total 2*32*4*24*64 = 393216
    int lane = gid & 63;
    int rem = gid >> 6;
    int kc = rem % 24;  rem /= 24;
    int wave = rem & 3; rem >>= 2;
    int ut = rem & 31;  rem >>= 5;
    int phase = rem;                                // 0=enc, 1=dec
    if (phase > 1) return;

    const float* Wih = phase ? dWih : eWih;
    const float* Whh = phase ? dWhh : eWhh;
    const int l15 = lane & 15, l4 = lane >> 4;
    const int grow = wave * H_ + ut * 16 + l15;     // gate row in [4H]
    const float* src = (kc < 8) ? (Wih + (size_t)grow * E_ + kc * 32 + l4 * 8)
                                : (Whh + (size_t)grow * H_ + (kc - 8) * 32 + l4 * 8);
    float4 v0 = reinterpret_cast<const float4*>(src)[0];
    float4 v1 = reinterpret_cast<const float4*>(src)[1];
    ushort f[8];
    f[0] = (ushort)f2bf(v0.x); f[1] = (ushort)f2bf(v0.y);
    f[2] = (ushort)f2bf(v0.z); f[3] = (ushort)f2bf(v0.w);
    f[4] = (ushort)f2bf(v1.x); f[5] = (ushort)f2bf(v1.y);
    f[6] = (ushort)f2bf(v1.z); f[7] = (ushort)f2bf(v1.w);
    *reinterpret_cast<uint4*>(wpack + (size_t)gid * 8) = *reinterpret_cast<uint4*>(f);
}

// ---------------------------------------------------------------------------
// One LSTM step (graph-launched 257x; kernel boundary = the h visibility sync).
// Grid: 256 wgs = 8 batch-tiles(32 rows) x 32 unit-tiles(16 units).
// Block: 256 = 4 waves; wave g owns gate g. Weights from wpack (24 uint4/thread).
__global__ __launch_bounds__(256)
void k_step(const ushort* __restrict__ xb, int xstr,
            const ushort* __restrict__ hc, ushort* __restrict__ hn,
            float* __restrict__ cb,
            const ushort* __restrict__ wpack_ph,   // this phase's pack
            const float* __restrict__ bih, const float* __restrict__ bhh,
            ushort* __restrict__ sv_t) {           // save slot base (+= tt*H done by host)
    __shared__ ushort Alds[96 * 32 * 8];           // 48KB
    __shared__ float zlds[4][2][16][17];
    __shared__ float blds[64];

    const int wg = blockIdx.x;
    const int bt = wg >> 5, ut = wg & 31;
    const int b0 = bt * 32, u0 = ut * 16;
    const int tid = threadIdx.x;
    const int wave = tid >> 6;
    const int lane = tid & 63;
    const int l15 = lane & 15, l4 = lane >> 4;
    const int cj = tid & 15, cr = tid >> 4;

    // ---- weights: 24 coalesced uint4 loads from the packed layout ----
    bf16x8 w[24];
    const ushort* wp = wpack_ph + ((size_t)(ut * 4 + wave) * 24 * 64) * 8;
#pragma unroll
    for (int kc = 0; kc < 24; ++kc)
        w[kc] = *reinterpret_cast<const bf16x8*>(wp + ((size_t)kc * 64 + lane) * 8);

    if (tid < 64) {
        int g = tid >> 4, j = tid & 15;
        blds[tid] = bih[g * H_ + u0 + j] + bhh[g * H_ + u0 + j];
    }

    // ---- stage A-tile: x part (kcs 0..31) then h part (kcs 32..95) ----
#pragma unroll
    for (int i = 0; i < 12; ++i) {
        int slot = i * 256 + tid;
        int kcs = slot >> 5, row = slot & 31;
        const ushort* src = (i < 4)
            ? (xb + (size_t)(b0 + row) * xstr + kcs * 8)
            : (hc + (size_t)(b0 + row) * H_ + (kcs - 32) * 8);
        uint4 v = *reinterpret_cast<const uint4*>(src);
        *reinterpret_cast<uint4*>(&Alds[slot * 8]) = v;
    }
    __syncthreads();

    // ---- MFMA: z[32 x 16cols] for this wave's gate ----
    f32x4 acc0 = {0.f, 0.f, 0.f, 0.f};
    f32x4 acc1 = {0.f, 0.f, 0.f, 0.f};
#pragma unroll
    for (int kc = 0; kc < 24; ++kc) {
        const int sbase = (kc * 4 + l4) * 32;
        bf16x8 a0 = *reinterpret_cast<const bf16x8*>(&Alds[(sbase + l15) * 8]);
        bf16x8 a1 = *reinterpret_cast<const bf16x8*>(&Alds[(sbase + 16 + l15) * 8]);
        acc0 = __builtin_amdgcn_mfma_f32_16x16x32_bf16(a0, w[kc], acc0, 0, 0, 0);
        acc1 = __builtin_amdgcn_mfma_f32_16x16x32_bf16(a1, w[kc], acc1, 0, 0, 0);
    }
    // C/D layout: col = lane&15, row = (lane>>4)*4 + reg  [m89-verified]
#pragma unroll
    for (int q = 0; q < 4; ++q) {
        zlds[wave][0][l4 * 4 + q][l15] = acc0[q];
        zlds[wave][1][l4 * 4 + q][l15] = acc1[q];
    }
    __syncthreads();

    // ---- cell update: thread owns (rows cr, cr+16) x unit cj ----
#pragma unroll
    for (int rr = 0; rr < 2; ++rr) {
        int r16 = cr + rr * 16;
        int row = b0 + r16;
        float zi = zlds[0][rr][cr][cj] + blds[cj];
        float zf = zlds[1][rr][cr][cj] + blds[16 + cj];
        float zg = zlds[2][rr][cr][cj] + blds[32 + cj];
        float zo = zlds[3][rr][cr][cj] + blds[48 + cj];
        float c_old = cb[(size_t)row * H_ + u0 + cj];
        float cn = sigm(zf) * c_old + sigm(zi) * tanhf(zg);
        float hv = sigm(zo) * tanhf(cn);
        cb[(size_t)row * H_ + u0 + cj] = cn;
        ushort hbits = (ushort)f2bf(hv);
        hn[(size_t)row * H_ + u0 + cj] = hbits;
        sv_t[(size_t)row * (T_ * H_) + u0 + cj] = hbits;
    }
}

// ---------------------------------------------------------------------------
// Batched attention + masked log-softmax + CE (unchanged from passing version)
constexpr int TT = 16;
__global__ __launch_bounds__(512)
void k_attn(const __hip_bfloat16* __restrict__ ext,
            const __hip_bfloat16* __restrict__ hdec,
            const int* __restrict__ pos, const int* __restrict__ tgt,
            float* __restrict__ loss) {
    __shared__ float ht[TT][H_];
    __shared__ float key[H_];
    __shared__ float lg[TT][T_ + 3];
    __shared__ float bl[TT];
    const int b = blockIdx.x / 9;
    const int t0 = (blockIdx.x % 9) * TT;
    const int tid = threadIdx.x;
    const int g = tid >> 5, l = tid & 31;

    for (int idx = tid; idx < TT * H_; idx += 512) {
        int tl = idx >> 9, u = idx & 511;
        int t = t0 + tl;
        ht[tl][u] = (t < T_) ? __bfloat162float(hdec[((size_t)b * T_ + t) * H_ + u]) : 0.f;
    }
    __syncthreads();

    for (int j = 0; j < T_; ++j) {
        key[tid] = __bfloat162float(ext[((size_t)b * T_ + j) * H_ + tid]);
        __syncthreads();
        float s = 0.f;
#pragma unroll
        for (int q = 0; q < H_ / 32; ++q) s += ht[g][l + q * 32] * key[l + q * 32];
        s += __shfl_xor(s, 16); s += __shfl_xor(s, 8); s += __shfl_xor(s, 4);
        s += __shfl_xor(s, 2);  s += __shfl_xor(s, 1);
        if (l == 0) {
            int t = t0 + g;
            lg[g][j] = (t < T_ && pos[b * T_ + j] < t) ? NEGV : s;
        }
        __syncthreads();
    }

    const int t = t0 + g;
    float mx = -3.4e38f;
    for (int j = l; j < T_; j += 32) mx = fmaxf(mx, lg[g][j]);
    mx = fmaxf(mx, __shfl_xor(mx, 16)); mx = fmaxf(mx, __shfl_xor(mx, 8));
    mx = fmaxf(mx, __shfl_xor(mx, 4));  mx = fmaxf(mx, __shfl_xor(mx, 2));
    mx = fmaxf(mx, __shfl_xor(mx, 1));
    float se = 0.f;
    for (int j = l; j < T_; j += 32) se += __expf(lg[g][j] - mx);
    se += __shfl_xor(se, 16); se += __shfl_xor(se, 8); se += __shfl_xor(se, 4);
    se += __shfl_xor(se, 2);  se += __shfl_xor(se, 1);
    float lval = 0.f;
    if (l == 0 && t < T_) {
        int tg = tgt[b * T_ + t];
        lval = mx + __logf(se) - lg[g][tg];
    }
    if (l == 0) bl[g] = (t < T_) ? lval : 0.f;
    __syncthreads();
    if (tid == 0) {
        float s = 0.f;
#pragma unroll
        for (int q = 0; q < TT; ++q) s += bl[q];
        atomicAdd(loss, s);
    }
}

__global__ void k_final(const float* __restrict__ loss, float* __restrict__ out) {
    out[0] = loss[0] / (float)(B_ * T_);
}

// ---------------------------------------------------------------------------
extern "C" void kernel_launch(void* const* d_in, const int* in_sizes, int n_in,
                              void* d_out, int out_size, void* d_ws, size_t ws_size,
                              hipStream_t stream) {
    const float* adj    = (const float*)d_in[0];
    const int*   tgt    = (const int*)d_in[1];
    const float* Wemb   = (const float*)d_in[2];
    const float* bemb   = (const float*)d_in[3];
    const float* eWih   = (const float*)d_in[4];
    const float* eWhh   = (const float*)d_in[5];
    const float* ebih   = (const float*)d_in[6];
    const float* ebhh   = (const float*)d_in[7];
    const float* dWih   = (const float*)d_in[8];
    const float* dWhh   = (const float*)d_in[9];
    const float* dbih   = (const float*)d_in[10];
    const float* dbhh   = (const float*)d_in[11];
    const float* dstart = (const float*)d_in[12];
    const float* eos    = (const float*)d_in[13];

    // workspace layout (bf16 activations)
    char* wsb = (char*)d_ws;
    ushort* ne    = (ushort*)wsb;  wsb += (size_t)B_ * N_ * E_ * 2;        // 16.8MB
    ushort* dxp   = (ushort*)wsb;  wsb += (size_t)B_ * T_ * E_ * 2;        // 16.9MB
    ushort* hb0   = (ushort*)wsb;  wsb += (size_t)B_ * H_ * 2;
    ushort* hb1   = (ushort*)wsb;  wsb += (size_t)B_ * H_ * 2;
    float*  cb    = (float*)wsb;   wsb += (size_t)B_ * H_ * 4;             // 0.5MB
    ushort* ext   = (ushort*)wsb;  wsb += (size_t)B_ * T_ * H_ * 2;        // 33.8MB
    ushort* hdec  = (ushort*)wsb;  wsb += (size_t)B_ * T_ * H_ * 2;        // 33.8MB
    ushort* wpack = (ushort*)wsb;  wsb += (size_t)2 * 32 * 4 * 24 * 64 * 8 * 2; // 6.3MB
    int*    pos   = (int*)wsb;     wsb += (size_t)B_ * T_ * 4;
    float*  lacc  = (float*)wsb;

    ushort* wpackE = wpack;
    ushort* wpackD = wpack + (size_t)32 * 4 * 24 * 64 * 8;

    k_embed<<<(B_ * N_) / 16, 256, 0, stream>>>(adj, Wemb, bemb, ne);
    k_init<<<(B_ * H_) / 256, 256, 0, stream>>>(tgt, eos, hb0, cb, lacc, pos, ext);
    k_decx<<<B_ * T_, 256, 0, stream>>>(tgt, ne, dstart, dxp);
    k_wprep<<<1536, 256, 0, stream>>>(eWih, eWhh, dWih, dWhh, wpack);

    ushort* hb[2] = {hb0, hb1};

    // encoder: 128 steps
    for (int t = 0; t < N_; ++t) {
        k_step<<<256, 256, 0, stream>>>(
            ne + (size_t)t * E_, N_ * E_,
            hb[t & 1], hb[(t + 1) & 1], cb,
            wpackE, ebih, ebhh,
            ext + (size_t)t * H_);
    }
    // decoder: 129 steps (h/c carry; parity continues)
    for (int t = 0; t < T_; ++t) {
        int s = N_ + t;
        k_step<<<256, 256, 0, stream>>>(
            dxp + (size_t)t * E_, T_ * E_,
            hb[s & 1], hb[(s + 1) & 1], cb,
            wpackD, dbih, dbhh,
            hdec + (size_t)t * H_);
    }

    k_attn<<<B_ * 9, 512, 0, stream>>>((const __hip_bfloat16*)ext,
                                       (const __hip_bfloat16*)hdec, pos, tgt, lacc);
    k_final<<<1, 1, 0, stream>>>(lacc, (float*)d_out);
}